// Round 6
// baseline (55.425 us; speedup 1.0000x reference)
//
#include <hip/hip_runtime.h>

#define RW 25            // floats per row: K + 24 LSP frequencies
#define RPB 256          // rows per block (== threads per block)

typedef float f4 __attribute__((ext_vector_type(4)));
typedef float f2 __attribute__((ext_vector_type(2)));

__global__ __launch_bounds__(256) void lsp2lpc_kernel(const float* __restrict__ in,
                                                      float* __restrict__ out) {
    __shared__ float sm[RPB * RW];   // 25.6 KB -> 6 blocks/CU
    const long long row0 = (long long)blockIdx.x * RPB;
    const f4* gin4 = (const f4*)(in + row0 * RW);
    f4* sm4 = (f4*)sm;
    const int tid = threadIdx.x;

    // coalesced vectorized global->LDS staging: 1600 float4 = 6*256 + 64
    #pragma unroll
    for (int i = 0; i < 6; ++i)
        sm4[tid + i * 256] = gin4[tid + i * 256];
    if (tid < 64)
        sm4[tid + 1536] = gin4[tid + 1536];
    __syncthreads();

    // each thread owns one row in LDS (stride 25: conflict-free, gcd(25,32)=1)
    const float* wr = &sm[tid * RW];
    const float K = wr[0];

    // packed coefficient pairs: c[k] = (-2cos w_p, -2cos w_q)
    // p roots from wf[1::2] = w[2],w[4],..,w[24]; q from wf[0::2] = w[1],..,w[23]
    f2 c[12];
    #pragma unroll
    for (int k = 0; k < 12; ++k) {
        c[k].x = -2.f * __cosf(wr[2 + 2 * k]);
        c[k].y = -2.f * __cosf(wr[1 + 2 * k]);
    }

    // PALINDROME: P = prod(x^2+ax+1) is self-reciprocal: P[j] == P[24-j].
    // Track only PQ[0..12] (packed P,Q). Update for factor a at step k
    // (old degree 2k): new[j] = old[j] + a*old[j-1] + old[j-2], and the
    // fresh top half-coefficient uses old[k+1] == old[k-1]:
    //   new[k+1] = a*old[k] + 2*old[k-1].
    f2 PQ[13];
    PQ[0] = (f2)(1.f);
    PQ[1] = c[0];
    #pragma unroll
    for (int j = 2; j < 13; ++j) PQ[j] = (f2)(0.f);

    #pragma unroll
    for (int k = 1; k < 12; ++k) {
        const f2 a = c[k];
        PQ[k + 1] = a * PQ[k] + 2.f * PQ[k - 1];
        #pragma unroll
        for (int j = k; j >= 2; --j)
            PQ[j] = PQ[j] + a * PQ[j - 1] + PQ[j - 2];
        PQ[1] = PQ[1] + a * PQ[0];   // PQ[0] stays 1
    }

    // epilogue, both halves from the stored half:
    //   pc[m] = P[m+1]-P[m], qc[m] = Q[m+1]+Q[m]   (m = 0..11)
    //   a[m]    = 0.5*( pc[m] + qc[m])
    //   a[23-m] = 0.5*(-pc[m] + qc[m])   (pc antisymmetric, qc symmetric)
    // Direct scalar global stores: a wave's 25 store instrs fully cover its
    // contiguous 6.4KB span back-to-back -> L2 assembles full lines.
    float* go = out + (row0 + tid) * RW;
    go[0] = K;
    #pragma unroll
    for (int m = 0; m < 12; ++m) {
        const float pcm = PQ[m + 1].x - PQ[m].x;
        const float qcm = PQ[m + 1].y + PQ[m].y;
        go[1 + m]      = 0.5f * (pcm + qcm);
        go[1 + 23 - m] = 0.5f * (qcm - pcm);
    }
}

extern "C" void kernel_launch(void* const* d_in, const int* in_sizes, int n_in,
                              void* d_out, int out_size, void* d_ws, size_t ws_size,
                              hipStream_t stream) {
    const float* in = (const float*)d_in[0];
    float* out = (float*)d_out;
    const int nrows = in_sizes[0] / RW;          // 16*65536 = 1,048,576
    const int nblocks = nrows / RPB;             // 4096 (exactly divisible)
    lsp2lpc_kernel<<<nblocks, RPB, 0, stream>>>(in, out);
}

// Round 7
// 36.531 us; speedup vs baseline: 1.5172x; 1.5172x over previous
//
#include <hip/hip_runtime.h>

#define RW 25            // floats per row: K + 24 LSP frequencies
#define RPB 256          // rows per block (== threads per block)

typedef float f4 __attribute__((ext_vector_type(4)));
typedef float f2 __attribute__((ext_vector_type(2)));

__global__ __launch_bounds__(256) void lsp2lpc_kernel(const float* __restrict__ in,
                                                      float* __restrict__ out) {
    __shared__ float sm[RPB * RW];   // 25.6 KB -> 6 blocks/CU
    const long long row0 = (long long)blockIdx.x * RPB;
    const f4* gin4  = (const f4*)(in  + row0 * RW);
    f4*       gout4 = (f4*)(out + row0 * RW);
    f4*       sm4   = (f4*)sm;
    const int tid = threadIdx.x;

    // coalesced vectorized global->LDS staging: 1600 float4 = 6*256 + 64
    #pragma unroll
    for (int i = 0; i < 6; ++i)
        sm4[tid + i * 256] = gin4[tid + i * 256];
    if (tid < 64)
        sm4[tid + 1536] = gin4[tid + 1536];
    __syncthreads();

    // each thread owns one row in LDS (stride 25: conflict-free, gcd(25,32)=1)
    const float* wr = &sm[tid * RW];
    const float K = wr[0];

    // packed coefficient pairs: c[k] = (-2cos w_p, -2cos w_q)
    // p roots from wf[1::2] = w[2],w[4],..,w[24]; q from wf[0::2] = w[1],..,w[23]
    f2 c[12];
    #pragma unroll
    for (int k = 0; k < 12; ++k) {
        c[k].x = -2.f * __cosf(wr[2 + 2 * k]);
        c[k].y = -2.f * __cosf(wr[1 + 2 * k]);
    }

    // PALINDROME: P = prod(x^2+ax+1) is self-reciprocal: P[j] == P[24-j].
    // Track only PQ[0..12] (packed P,Q). Update for factor a at step k
    // (old degree 2k): new[j] = old[j] + a*old[j-1] + old[j-2]; fresh top
    // half-coefficient uses old[k+1] == old[k-1]: new[k+1] = a*old[k] + 2*old[k-1].
    f2 PQ[13];
    PQ[0] = (f2)(1.f);
    PQ[1] = c[0];
    #pragma unroll
    for (int j = 2; j < 13; ++j) PQ[j] = (f2)(0.f);

    #pragma unroll
    for (int k = 1; k < 12; ++k) {
        const f2 a = c[k];
        PQ[k + 1] = a * PQ[k] + 2.f * PQ[k - 1];
        #pragma unroll
        for (int j = k; j >= 2; --j)
            PQ[j] = PQ[j] + a * PQ[j - 1] + PQ[j - 2];
        PQ[1] = PQ[1] + a * PQ[0];   // PQ[0] stays 1
    }

    // epilogue into own LDS row (own-row reads above -> no barrier needed):
    //   pc[m] = P[m+1]-P[m], qc[m] = Q[m+1]+Q[m]   (m = 0..11)
    //   a[m]    = 0.5*( pc[m] + qc[m])
    //   a[23-m] = 0.5*( qc[m] - pc[m])   (pc antisymmetric, qc symmetric)
    float* orow = &sm[tid * RW];
    orow[0] = K;
    #pragma unroll
    for (int m = 0; m < 12; ++m) {
        const float pcm = PQ[m + 1].x - PQ[m].x;
        const float qcm = PQ[m + 1].y + PQ[m].y;
        orow[1 + m]      = 0.5f * (pcm + qcm);
        orow[1 + 23 - m] = 0.5f * (qcm - pcm);
    }
    __syncthreads();

    // coalesced vectorized LDS->global store (the proven R3 path)
    #pragma unroll
    for (int i = 0; i < 6; ++i)
        gout4[tid + i * 256] = sm4[tid + i * 256];
    if (tid < 64)
        gout4[tid + 1536] = sm4[tid + 1536];
}

extern "C" void kernel_launch(void* const* d_in, const int* in_sizes, int n_in,
                              void* d_out, int out_size, void* d_ws, size_t ws_size,
                              hipStream_t stream) {
    const float* in = (const float*)d_in[0];
    float* out = (float*)d_out;
    const int nrows = in_sizes[0] / RW;          // 16*65536 = 1,048,576
    const int nblocks = nrows / RPB;             // 4096 (exactly divisible)
    lsp2lpc_kernel<<<nblocks, RPB, 0, stream>>>(in, out);
}